// Round 14
// baseline (1357.562 us; speedup 1.0000x reference)
//
#include <hip/hip_runtime.h>

// MultiAgentDRQN R14. R13 lesson: gate-split kills PARALLEL kernels (low
// arith intensity) but is the right shape for the RECURRENT one IF each wave
// carries enough work. Fuse gi INTO the recurrent kernel:
//   gru6_k: 3 waves = 1 seq. Wave g holds Wih_g + Whh_g rows (128 wt floats,
//           at the 128-VGPR cap -> only ~20 remat vs gru3's ~100). Per step:
//           gi_g = Wih_g a(t), gh_g = Whh_g h(t) (interleaved k-loop, LDS
//           same-address broadcast reads = free); r/z publish sigmoids;
//           barrier; n-wave: h' = (1-z)tanh(gi_n + r gh_n)+z h, hs dbuf,
//           fc2+max/argmax inline (W2/b2 from L1, saves 16 VGPRs); barrier.
//           a(t) streamed via LDS dbuf, published by r-wave.
//   Eliminates gi_k AND 614 MB of gi HBM round-trip. ws needs only 100 MB.
//   fc1_k unchanged (R8 split-K). Fallback: R1 fused kernel.

namespace {
constexpr int kB = 256, kT = 200, kN = 8, kObs = 128, kH = 64, kOut = 16;
constexpr int kRows = kB * kT * kN;                  // 409600
constexpr size_t kABytes = (size_t)kRows * 64 * 4;   // 100 MB
}

// ------- fc1_k: a[r][64] = relu(x_r . W1^T + b1), split-K 2 waves/row --------
__global__ __launch_bounds__(256, 2)
void fc1_k(const float* __restrict__ obs, const int* __restrict__ agent,
           const float* __restrict__ W1, const float* __restrict__ b1,
           float* __restrict__ a_out) {
  __shared__ float xs[2][2][128];   // [engine][buf][k]
  __shared__ float ps[2][2][64];    // [engine][buf][out] partial sums
  __shared__ float ohs[512];        // ohs[n*64+l] = W1[l][128+agent[n]]
  const int tid = threadIdx.x, lane = tid & 63, w = tid >> 6;
  const int e = w >> 1, p = w & 1;  // engine, k-half

  for (int i = tid; i < 512; i += 256) {
    int n = i >> 6, l = i & 63;
    ohs[i] = W1[(size_t)l * 136 + 128 + agent[n]];
  }

  float4 wv[16];
  #pragma unroll
  for (int k = 0; k < 16; ++k)
    wv[k] = *(const float4*)(W1 + (size_t)lane * 136 + p * 64 + k * 4);
  const float b1r = b1[lane];       // used by finishing wave (p==1)

  constexpr int ROWS = 100;         // 4096 engines x 100 rows = 409600
  const int eng = blockIdx.x * 2 + e;
  const int r0 = eng * ROWS;
  const int et = p * 64 + lane;     // engine-local staging index [0,128)

  xs[e][0][et] = obs[(size_t)r0 * 128 + et];
  float xq = obs[(size_t)(r0 + 1) * 128 + et];
  __syncthreads();                  // covers ohs + row-0 staging

  #pragma unroll 1
  for (int i = 0; i < ROWS; ++i) {
    const int r = r0 + i;
    if (i + 1 < ROWS) xs[e][(i + 1) & 1][et] = xq;
    const int nr = (i + 2 < ROWS) ? (r0 + i + 2) : (r0 + ROWS - 1);
    xq = obs[(size_t)nr * 128 + et];

    const float* xb = xs[e][i & 1] + p * 64;
    float a0 = 0.f, a1 = 0.f, a2 = 0.f, a3 = 0.f;
    #pragma unroll
    for (int k = 0; k < 16; ++k) {
      float4 xp = *(const float4*)(xb + k * 4);   // same-addr broadcast read
      a0 = fmaf(wv[k].x, xp.x, a0);
      a1 = fmaf(wv[k].y, xp.y, a1);
      a2 = fmaf(wv[k].z, xp.z, a2);
      a3 = fmaf(wv[k].w, xp.w, a3);
    }
    const float part = (a0 + a1) + (a2 + a3);
    if (p == 0) ps[e][i & 1][lane] = part;
    __syncthreads();                // ps(i) visible; dbuf protects i+2 reuse
    if (p == 1) {
      float av = part + ps[e][i & 1][lane] + b1r + ohs[(r & 7) * 64 + lane];
      a_out[(size_t)r * 64 + lane] = fmaxf(av, 0.f);
    }
  }
}

// ---- gru6_k: fused gi+GRU+fc2. 3 waves = 1 seq (gate-split r/z/n) -----------
__global__ __launch_bounds__(192, 2)
void gru6_k(const float* __restrict__ a_glob,
            const float* __restrict__ Wih, const float* __restrict__ bih,
            const float* __restrict__ Whh, const float* __restrict__ bhh,
            const float* __restrict__ W2, const float* __restrict__ b2,
            float* __restrict__ out) {
  __shared__ float a_lds[2][64];
  __shared__ float hsb[2][64];
  __shared__ float rgs[64];
  __shared__ float zgs[64];
  const int tid = threadIdx.x, lane = tid & 63, g = tid >> 6; // 0=r,1=z,2=n

  // gate g's weight rows: Wih[g*64+lane][:], Whh[g*64+lane][:] (128 floats)
  float wi[64], wh[64];
  #pragma unroll
  for (int k = 0; k < 64; k += 4) {
    *(float4*)&wi[k] = *(const float4*)(Wih + (size_t)(g * 64 + lane) * 64 + k);
    *(float4*)&wh[k] = *(const float4*)(Whh + (size_t)(g * 64 + lane) * 64 + k);
  }
  const float big = bih[g * 64 + lane], bhg = bhh[g * 64 + lane];
  const int m = lane & 15, qt = lane >> 4;

  const int s = blockIdx.x;               // sequence = b*8 + n
  const size_t rbase = (size_t)(s >> 3) * 1600 + (s & 7);  // r(t)=rbase+8t

  float* outq  = out;
  float* outmv = out + (size_t)kRows * 16;
  float* outma = outmv + kRows;

  float h = 0.f;                          // live on n-wave
  float aq = 0.f;                         // a(t+1) lookahead, live on r-wave
  if (g == 0) {
    a_lds[0][lane] = a_glob[rbase * 64 + lane];           // a(0)
    aq = a_glob[(rbase + 8) * 64 + lane];                 // a(1)
  }
  if (g == 2) hsb[0][lane] = 0.f;
  __syncthreads();

#define G6_STEP(T, CUR, NXT, TN)                                               \
  {                                                                            \
    const float* ab_ = a_lds[CUR];                                             \
    const float* hb_ = hsb[CUR];                                               \
    float gi0 = big, gi1 = 0.f, gh0 = bhg, gh1 = 0.f;                          \
    _Pragma("unroll") for (int k = 0; k < 64; k += 4) {                        \
      float4 av = *(const float4*)(ab_ + k);   /* broadcast */                 \
      float4 hv = *(const float4*)(hb_ + k);   /* broadcast */                 \
      gi0 = fmaf(wi[k],     av.x, gi0); gi1 = fmaf(wi[k + 1], av.y, gi1);      \
      gi0 = fmaf(wi[k + 2], av.z, gi0); gi1 = fmaf(wi[k + 3], av.w, gi1);      \
      gh0 = fmaf(wh[k],     hv.x, gh0); gh1 = fmaf(wh[k + 1], hv.y, gh1);      \
      gh0 = fmaf(wh[k + 2], hv.z, gh0); gh1 = fmaf(wh[k + 3], hv.w, gh1);      \
    }                                                                          \
    const float gi_ = gi0 + gi1, gh_ = gh0 + gh1;                              \
    if (g == 0) {                                                              \
      rgs[lane] = 1.f / (1.f + __expf(-(gi_ + gh_)));                          \
      a_lds[NXT][lane] = aq;                /* publish a(t+1) */               \
      const int tn_ = (TN) > 199 ? 199 : (TN);                                 \
      aq = a_glob[(rbase + (size_t)tn_ * 8) * 64 + lane];  /* a(t+2) */        \
    } else if (g == 1) {                                                       \
      zgs[lane] = 1.f / (1.f + __expf(-(gi_ + gh_)));                          \
    }                                                                          \
    __syncthreads();                        /* A: rgs,zgs,a_lds[NXT] */        \
    if (g == 2) {                                                              \
      const size_t r_ = rbase + (size_t)(T) * 8;                               \
      const float rg_ = rgs[lane], zg_ = zgs[lane];                            \
      const float e2_ = __expf(2.f * (gi_ + rg_ * gh_));                       \
      const float ng_ = 1.f - 2.f / (e2_ + 1.f);    /* tanh */                 \
      h = (1.f - zg_) * ng_ + zg_ * h;                                         \
      hsb[NXT][lane] = h;                                                      \
      /* fc2 from hsb[NXT]: own-wave write->read is ordered */                 \
      float q0 = 0.f, q1 = 0.f;                                                \
      _Pragma("unroll") for (int j = 0; j < 16; j += 4) {                      \
        float4 hv = *(const float4*)(hsb[NXT] + qt * 16 + j);                  \
        float4 wv = *(const float4*)(W2 + (size_t)m * 64 + qt * 16 + j);       \
        q0 = fmaf(wv.x, hv.x, q0); q1 = fmaf(wv.y, hv.y, q1);                  \
        q0 = fmaf(wv.z, hv.z, q0); q1 = fmaf(wv.w, hv.w, q1);                  \
      }                                                                        \
      float q = q0 + q1;                                                       \
      q += __shfl_xor(q, 16);                                                  \
      q += __shfl_xor(q, 32);                                                  \
      q += b2[m];                                                              \
      if (lane < 16) outq[r_ * 16 + m] = q;                                    \
      float bv = q; int bi = m;                                                \
      _Pragma("unroll") for (int d = 1; d < 16; d <<= 1) {                     \
        float ov = __shfl_xor(bv, d, 16);                                      \
        int oi = __shfl_xor(bi, d, 16);                                        \
        if (ov > bv || (ov == bv && oi < bi)) { bv = ov; bi = oi; }            \
      }                                                                        \
      if (lane == 0) { outmv[r_] = bv; outma[r_] = (float)bi; }                \
    }                                                                          \
    __syncthreads();                        /* B: hsb[NXT] visible */          \
  }

  #pragma unroll 1
  for (int t = 0; t < 200; t += 2) {
    G6_STEP(t,     0, 1, t + 2)
    G6_STEP(t + 1, 1, 0, t + 3)
  }
#undef G6_STEP
}

// ---------------- R1 fallback (no/small workspace) ---------------------------
namespace fb {
constexpr int kW1Pitch = 137, kHPitch = 65;
constexpr int OFF_W1 = 0;
constexpr int OFF_WIH = OFF_W1 + 64 * kW1Pitch;
constexpr int OFF_WHH = OFF_WIH + 192 * kHPitch;
constexpr int OFF_W2 = OFF_WHH + 192 * kHPitch;
constexpr int OFF_B1 = OFF_W2 + 16 * kHPitch;
constexpr int OFF_BIH = OFF_B1 + 64;
constexpr int OFF_BHH = OFF_BIH + 192;
constexpr int OFF_B2 = OFF_BHH + 192;
constexpr int LDS_FLOATS = OFF_B2 + 16;
}

__device__ __forceinline__ float bcastf(float v, int l) {
  return __int_as_float(__builtin_amdgcn_readlane(__float_as_int(v), l));
}

__global__ __launch_bounds__(512, 1)
void drqn_fused(const float* __restrict__ obs, const int* __restrict__ agent,
                const float* __restrict__ W1, const float* __restrict__ b1,
                const float* __restrict__ Wih, const float* __restrict__ Whh,
                const float* __restrict__ bih, const float* __restrict__ bhh,
                const float* __restrict__ W2, const float* __restrict__ b2,
                float* __restrict__ out) {
  using namespace fb;
  extern __shared__ float lds[];
  float* W1s = lds + OFF_W1; float* Wihs = lds + OFF_WIH;
  float* Whhs = lds + OFF_WHH; float* W2s = lds + OFF_W2;
  float* b1s = lds + OFF_B1; float* bihs = lds + OFF_BIH;
  float* bhhs = lds + OFF_BHH; float* b2s = lds + OFF_B2;
  const int tid = threadIdx.x;
  for (int i = tid; i < 64 * 136; i += 512) { int r = i / 136, c = i - r * 136; W1s[r * kW1Pitch + c] = W1[i]; }
  for (int i = tid; i < 192 * 64; i += 512) { int r = i >> 6, c = i & 63; Wihs[r * kHPitch + c] = Wih[i]; }
  for (int i = tid; i < 192 * 64; i += 512) { int r = i >> 6, c = i & 63; Whhs[r * kHPitch + c] = Whh[i]; }
  for (int i = tid; i < 16 * 64; i += 512) { int r = i >> 6, c = i & 63; W2s[r * kHPitch + c] = W2[i]; }
  if (tid < 64) b1s[tid] = b1[tid];
  if (tid < 192) bihs[tid] = bih[tid];
  if (tid < 192) bhhs[tid] = bhh[tid];
  if (tid < 16) b2s[tid] = b2[tid];
  __syncthreads();
  const int wave = tid >> 6, lane = tid & 63;
  const int s = blockIdx.x * 8 + wave;
  const int b = s >> 3, n = s & 7;
  const int acol = 128 + agent[n];
  const float* obase = obs + (((size_t)b * kT) * kN + n) * kObs;
  const size_t qbase = (((size_t)b * kT) * kN + n) * kOut;
  const size_t mbase = ((size_t)b * kT) * kN + n;
  float* outq = out;
  float* outmv = out + (size_t)kB * kT * kN * kOut;
  float* outma = outmv + (size_t)kB * kT * kN;
  float h = 0.f;
  float xa = obase[lane], xb = obase[64 + lane];
  #pragma unroll 1
  for (int t = 0; t < kT; ++t) {
    float xan = 0.f, xbn = 0.f;
    if (t + 1 < kT) { const float* p = obase + (size_t)(t + 1) * kN * kObs; xan = p[lane]; xbn = p[64 + lane]; }
    float acc = b1s[lane] + W1s[lane * kW1Pitch + acol];
    #pragma unroll
    for (int k = 0; k < 64; ++k) acc += W1s[lane * kW1Pitch + k] * bcastf(xa, k);
    #pragma unroll
    for (int k = 0; k < 64; ++k) acc += W1s[lane * kW1Pitch + 64 + k] * bcastf(xb, k);
    float a = fmaxf(acc, 0.f);
    float air = bihs[lane], aiz = bihs[64 + lane], ain = bihs[128 + lane];
    #pragma unroll
    for (int k = 0; k < 64; ++k) {
      float sa = bcastf(a, k);
      air += Wihs[lane * kHPitch + k] * sa;
      aiz += Wihs[(64 + lane) * kHPitch + k] * sa;
      ain += Wihs[(128 + lane) * kHPitch + k] * sa;
    }
    float ghr = bhhs[lane], ghz = bhhs[64 + lane], ghn = bhhs[128 + lane];
    #pragma unroll
    for (int k = 0; k < 64; ++k) {
      float sh = bcastf(h, k);
      ghr += Whhs[lane * kHPitch + k] * sh;
      ghz += Whhs[(64 + lane) * kHPitch + k] * sh;
      ghn += Whhs[(128 + lane) * kHPitch + k] * sh;
    }
    float rg = 1.f / (1.f + expf(-(air + ghr)));
    float zg = 1.f / (1.f + expf(-(aiz + ghz)));
    float ng = tanhf(ain + rg * ghn);
    h = (1.f - zg) * ng + zg * h;
    const int m = lane & 15;
    float q = b2s[m];
    #pragma unroll
    for (int k = 0; k < 64; ++k) q += W2s[m * kHPitch + k] * bcastf(h, k);
    if (lane < 16) outq[qbase + (size_t)t * kN * kOut + m] = q;
    float bv = q; int bi = m;
    #pragma unroll
    for (int d = 1; d < 16; d <<= 1) {
      float ov = __shfl_xor(bv, d, 16);
      int oi = __shfl_xor(bi, d, 16);
      if (ov > bv || (ov == bv && oi < bi)) { bv = ov; bi = oi; }
    }
    if (lane == 0) { outmv[mbase + (size_t)t * kN] = bv; outma[mbase + (size_t)t * kN] = (float)bi; }
    xa = xan; xb = xbn;
  }
}

extern "C" void kernel_launch(void* const* d_in, const int* in_sizes, int n_in,
                              void* d_out, int out_size, void* d_ws, size_t ws_size,
                              hipStream_t stream) {
  const float* obs  = (const float*)d_in[0];
  const int* agent  = (const int*)d_in[1];
  const float* W1   = (const float*)d_in[2];
  const float* b1   = (const float*)d_in[3];
  const float* Wih  = (const float*)d_in[4];
  const float* Whh  = (const float*)d_in[5];
  const float* bih  = (const float*)d_in[6];
  const float* bhh  = (const float*)d_in[7];
  const float* W2   = (const float*)d_in[8];
  const float* b2   = (const float*)d_in[9];
  float* out = (float*)d_out;

  if (ws_size >= kABytes) {
    float* a_buf = (float*)d_ws;
    fc1_k <<<dim3(2048), dim3(256), 0, stream>>>(obs, agent, W1, b1, a_buf);
    gru6_k<<<dim3(2048), dim3(192), 0, stream>>>(a_buf, Wih, bih, Whh, bhh,
                                                 W2, b2, out);
  } else {
    (void)hipFuncSetAttribute((const void*)drqn_fused,
                              hipFuncAttributeMaxDynamicSharedMemorySize,
                              fb::LDS_FLOATS * 4);
    drqn_fused<<<dim3(256), dim3(512), fb::LDS_FLOATS * 4, stream>>>(
        obs, agent, W1, b1, Wih, Whh, bih, bhh, W2, b2, out);
  }
}

// Round 15
// 844.212 us; speedup vs baseline: 1.6081x; 1.6081x over previous
//
#include <hip/hip_runtime.h>

// MultiAgentDRQN R15. Ledger: allocator caps ~128 VGPR regardless of hints
// (R10/R11/R14); 192-float weight sets always reload; gate-split(64) starves
// waves; 2-seq starves TLP. Best = R10 (596us: fc1 150, gi 155, gru3 290).
// This round: revert to R10, replace gru3 with gru7_k = split-K 2 waves/seq:
//   wave p holds Whh rows {l,64+l,128+l}, k in [p*32,p*32+32) = 96 floats
//   (+~25 temps ~ 120 < 128 cap -> FITS, no reloads by construction).
//   Step: 96 FMA matvec; wave0 -> ps partials; barrier A; wave1 combines,
//   gates, h' -> hs (single-buffered: writes after A, matvec reads before A),
//   fc2 (W2 via L1) + max/argmax; barrier B. 4096 waves = 4/SIMD (2x TLP).
// fc1_k (R8 split-K) / gi_k (R4) unchanged. Fallback: R1 fused kernel.

namespace {
constexpr int kB = 256, kT = 200, kN = 8, kObs = 128, kH = 64, kOut = 16;
constexpr int kRows = kB * kT * kN;                  // 409600
constexpr size_t kABytes  = (size_t)kRows * 64 * 4;  // 100 MB
constexpr size_t kGiBytes = (size_t)kRows * 192 * 4; // 300 MB
}

// ------- fc1_k: a[r][64] = relu(x_r . W1^T + b1), split-K 2 waves/row --------
__global__ __launch_bounds__(256, 2)
void fc1_k(const float* __restrict__ obs, const int* __restrict__ agent,
           const float* __restrict__ W1, const float* __restrict__ b1,
           float* __restrict__ a_out) {
  __shared__ float xs[2][2][128];   // [engine][buf][k]
  __shared__ float ps[2][2][64];    // [engine][buf][out] partial sums
  __shared__ float ohs[512];        // ohs[n*64+l] = W1[l][128+agent[n]]
  const int tid = threadIdx.x, lane = tid & 63, w = tid >> 6;
  const int e = w >> 1, p = w & 1;  // engine, k-half

  for (int i = tid; i < 512; i += 256) {
    int n = i >> 6, l = i & 63;
    ohs[i] = W1[(size_t)l * 136 + 128 + agent[n]];
  }

  float4 wv[16];
  #pragma unroll
  for (int k = 0; k < 16; ++k)
    wv[k] = *(const float4*)(W1 + (size_t)lane * 136 + p * 64 + k * 4);
  const float b1r = b1[lane];       // used by finishing wave (p==1)

  constexpr int ROWS = 100;         // 4096 engines x 100 rows = 409600
  const int eng = blockIdx.x * 2 + e;
  const int r0 = eng * ROWS;
  const int et = p * 64 + lane;     // engine-local staging index [0,128)

  xs[e][0][et] = obs[(size_t)r0 * 128 + et];
  float xq = obs[(size_t)(r0 + 1) * 128 + et];
  __syncthreads();                  // covers ohs + row-0 staging

  #pragma unroll 1
  for (int i = 0; i < ROWS; ++i) {
    const int r = r0 + i;
    if (i + 1 < ROWS) xs[e][(i + 1) & 1][et] = xq;
    const int nr = (i + 2 < ROWS) ? (r0 + i + 2) : (r0 + ROWS - 1);
    xq = obs[(size_t)nr * 128 + et];

    const float* xb = xs[e][i & 1] + p * 64;
    float a0 = 0.f, a1 = 0.f, a2 = 0.f, a3 = 0.f;
    #pragma unroll
    for (int k = 0; k < 16; ++k) {
      float4 xp = *(const float4*)(xb + k * 4);   // same-addr broadcast read
      a0 = fmaf(wv[k].x, xp.x, a0);
      a1 = fmaf(wv[k].y, xp.y, a1);
      a2 = fmaf(wv[k].z, xp.z, a2);
      a3 = fmaf(wv[k].w, xp.w, a3);
    }
    const float part = (a0 + a1) + (a2 + a3);
    if (p == 0) ps[e][i & 1][lane] = part;
    __syncthreads();                // ps(i) visible; dbuf protects i+2 reuse
    if (p == 1) {
      float av = part + ps[e][i & 1][lane] + b1r + ohs[(r & 7) * 64 + lane];
      a_out[(size_t)r * 64 + lane] = fmaxf(av, 0.f);
    }
  }
}

// ---------------- gi_k: gi[r][192] = Wih . a_r + bih -------------------------
__global__ __launch_bounds__(256, 2)
void gi_k(const float* __restrict__ a_glob, const float* __restrict__ Wih,
          const float* __restrict__ bih, float* __restrict__ gi_out) {
  __shared__ float as_[4][2][64];
  const int tid = threadIdx.x, lane = tid & 63, w = tid >> 6;

  float wir[64], wiz[64], win_[64];
  #pragma unroll
  for (int k = 0; k < 64; k += 4) {
    *(float4*)&wir[k]  = *(const float4*)(Wih + (size_t)lane * 64 + k);
    *(float4*)&wiz[k]  = *(const float4*)(Wih + (size_t)(64 + lane) * 64 + k);
    *(float4*)&win_[k] = *(const float4*)(Wih + (size_t)(128 + lane) * 64 + k);
  }
  const float bir = bih[lane], biz = bih[64 + lane], bin_ = bih[128 + lane];

  const int gwave = blockIdx.x * 4 + w;   // 2048 waves x 200 rows
  const int r0 = gwave * 200;
  float (*ab)[64] = as_[w];

  ab[0][lane] = a_glob[(size_t)r0 * 64 + lane];
  float qA = a_glob[(size_t)(r0 + 1) * 64 + lane];
  float qB = a_glob[(size_t)(r0 + 2) * 64 + lane];

#define GI_BODY(T, Q, NEXT)                                                    \
  {                                                                            \
    const int t_ = (T);                                                        \
    if (t_ < 199) ab[(t_ + 1) & 1][lane] = Q;                                  \
    const int nr_ = (NEXT) > 199 ? 199 : (NEXT);                               \
    Q = a_glob[(size_t)(r0 + nr_) * 64 + lane];                                \
    const float* ap_ = ab[t_ & 1];                                             \
    float r0a = bir, r1a = 0.f, z0a = biz, z1a = 0.f, n0a = bin_, n1a = 0.f;   \
    _Pragma("unroll") for (int k = 0; k < 64; k += 4) {                        \
      float4 av = *(const float4*)(ap_ + k);                                   \
      r0a = fmaf(wir[k], av.x, r0a);  r1a = fmaf(wir[k + 1], av.y, r1a);       \
      r0a = fmaf(wir[k + 2], av.z, r0a); r1a = fmaf(wir[k + 3], av.w, r1a);    \
      z0a = fmaf(wiz[k], av.x, z0a);  z1a = fmaf(wiz[k + 1], av.y, z1a);       \
      z0a = fmaf(wiz[k + 2], av.z, z0a); z1a = fmaf(wiz[k + 3], av.w, z1a);    \
      n0a = fmaf(win_[k], av.x, n0a); n1a = fmaf(win_[k + 1], av.y, n1a);      \
      n0a = fmaf(win_[k + 2], av.z, n0a); n1a = fmaf(win_[k + 3], av.w, n1a);  \
    }                                                                          \
    float* gp_ = gi_out + (size_t)(r0 + t_) * 192;                             \
    gp_[lane] = r0a + r1a;                                                     \
    gp_[64 + lane] = z0a + z1a;                                                \
    gp_[128 + lane] = n0a + n1a;                                               \
  }

  #pragma unroll 1
  for (int i = 0; i < 200; i += 2) {
    GI_BODY(i + 0, qA, i + 3)
    GI_BODY(i + 1, qB, i + 4)
  }
#undef GI_BODY
}

// ---- gru7_k: split-K 2 waves/seq; 96 wt floats/lane (fits the cap) ----------
__global__ __launch_bounds__(128, 2)
void gru7_k(const float* __restrict__ gi_glob,
            const float* __restrict__ Whh, const float* __restrict__ bhh,
            const float* __restrict__ W2, const float* __restrict__ b2,
            float* __restrict__ out) {
  __shared__ float hs[64];       // single-buffered h (write after A, read pre-A)
  __shared__ float ps[3][64];    // wave0 partials   (write pre-A, read A..B)
  const int tid = threadIdx.x, lane = tid & 63, p = tid >> 6;  // p = k-half

  // Whh rows {lane, 64+lane, 128+lane}, cols [p*32, p*32+32): 96 floats
  float wr[32], wz[32], wn[32];
  #pragma unroll
  for (int k = 0; k < 32; k += 4) {
    *(float4*)&wr[k] = *(const float4*)(Whh + (size_t)lane * 64 + p * 32 + k);
    *(float4*)&wz[k] = *(const float4*)(Whh + (size_t)(64 + lane) * 64 + p * 32 + k);
    *(float4*)&wn[k] = *(const float4*)(Whh + (size_t)(128 + lane) * 64 + p * 32 + k);
  }
  const float bhr = bhh[lane], bhz = bhh[64 + lane], bhn = bhh[128 + lane];
  const int m = lane & 15, qt = lane >> 4;

  const int s = blockIdx.x;               // sequence = b*8 + n
  const size_t rbase = (size_t)(s >> 3) * 1600 + (s & 7);  // r(t)=rbase+8t

  float* outq  = out;
  float* outmv = out + (size_t)kRows * 16;
  float* outma = outmv + kRows;

  float h = 0.f;
  if (p == 0) hs[lane] = 0.f;

  // gi prefetch on wave1 only (values used there)
  float gA0 = 0.f, gA1 = 0.f, gA2 = 0.f, gB0 = 0.f, gB1 = 0.f, gB2 = 0.f;
  if (p == 1) {
    const float* g0 = gi_glob + rbase * 192;
    gA0 = g0[lane]; gA1 = g0[64 + lane]; gA2 = g0[128 + lane];
    const float* g1 = gi_glob + (rbase + 8) * 192;
    gB0 = g1[lane]; gB1 = g1[64 + lane]; gB2 = g1[128 + lane];
  }
  __syncthreads();

#define G7_STEP(T, G0, G1, G2, TN)                                             \
  {                                                                            \
    /* matvec over own k-half: reads hs BEFORE barrier A */                    \
    const float* hb_ = hs + p * 32;                                            \
    float ar = 0.f, az = 0.f, an = 0.f;                                        \
    _Pragma("unroll") for (int k = 0; k < 32; k += 4) {                        \
      float4 hv = *(const float4*)(hb_ + k);      /* broadcast read */         \
      ar = fmaf(wr[k], hv.x, ar);     az = fmaf(wz[k], hv.x, az);              \
      an = fmaf(wn[k], hv.x, an);                                              \
      ar = fmaf(wr[k + 1], hv.y, ar); az = fmaf(wz[k + 1], hv.y, az);          \
      an = fmaf(wn[k + 1], hv.y, an);                                          \
      ar = fmaf(wr[k + 2], hv.z, ar); az = fmaf(wz[k + 2], hv.z, az);          \
      an = fmaf(wn[k + 2], hv.z, an);                                          \
      ar = fmaf(wr[k + 3], hv.w, ar); az = fmaf(wz[k + 3], hv.w, az);          \
      an = fmaf(wn[k + 3], hv.w, an);                                          \
    }                                                                          \
    if (p == 0) { ps[0][lane] = ar; ps[1][lane] = az; ps[2][lane] = an; }      \
    __syncthreads();                              /* A: partials visible */    \
    if (p == 1) {                                                              \
      const size_t r_ = rbase + (size_t)(T) * 8;                               \
      const float ghr = ar + ps[0][lane] + bhr;                                \
      const float ghz = az + ps[1][lane] + bhz;                                \
      const float ghn = an + ps[2][lane] + bhn;                                \
      const float rg = 1.f / (1.f + __expf(-((G0) + ghr)));                    \
      const float zg = 1.f / (1.f + __expf(-((G1) + ghz)));                    \
      const float e2 = __expf(2.f * ((G2) + rg * ghn));                        \
      const float ng = 1.f - 2.f / (e2 + 1.f);    /* tanh */                   \
      h = (1.f - zg) * ng + zg * h;                                            \
      hs[lane] = h;                               /* h(t+1), after A */        \
      const int tn_ = (TN) > 199 ? 199 : (TN);                                 \
      const float* gp_ = gi_glob + (rbase + (size_t)tn_ * 8) * 192;            \
      G0 = gp_[lane]; G1 = gp_[64 + lane]; G2 = gp_[128 + lane];               \
      /* fc2 from hs (own-wave write->read ordered) + max/argmax */            \
      float q0 = 0.f, q1 = 0.f;                                                \
      _Pragma("unroll") for (int j = 0; j < 16; j += 4) {                      \
        float4 hv = *(const float4*)(hs + qt * 16 + j);                        \
        float4 wv = *(const float4*)(W2 + (size_t)m * 64 + qt * 16 + j);       \
        q0 = fmaf(wv.x, hv.x, q0); q1 = fmaf(wv.y, hv.y, q1);                  \
        q0 = fmaf(wv.z, hv.z, q0); q1 = fmaf(wv.w, hv.w, q1);                  \
      }                                                                        \
      float q = q0 + q1;                                                       \
      q += __shfl_xor(q, 16);                                                  \
      q += __shfl_xor(q, 32);                                                  \
      q += b2[m];                                                              \
      if (lane < 16) outq[r_ * 16 + m] = q;                                    \
      float bv = q; int bi = m;                                                \
      _Pragma("unroll") for (int d = 1; d < 16; d <<= 1) {                     \
        float ov = __shfl_xor(bv, d, 16);                                      \
        int oi = __shfl_xor(bi, d, 16);                                        \
        if (ov > bv || (ov == bv && oi < bi)) { bv = ov; bi = oi; }            \
      }                                                                        \
      if (lane == 0) { outmv[r_] = bv; outma[r_] = (float)bi; }                \
    }                                                                          \
    __syncthreads();                              /* B: h(t+1) visible */      \
  }

  #pragma unroll 1
  for (int t = 0; t < 200; t += 2) {
    G7_STEP(t,     gA0, gA1, gA2, t + 2)
    G7_STEP(t + 1, gB0, gB1, gB2, t + 3)
  }
#undef G7_STEP
}

// ---------------- R1 fallback (no/small workspace) ---------------------------
namespace fb {
constexpr int kW1Pitch = 137, kHPitch = 65;
constexpr int OFF_W1 = 0;
constexpr int OFF_WIH = OFF_W1 + 64 * kW1Pitch;
constexpr int OFF_WHH = OFF_WIH + 192 * kHPitch;
constexpr int OFF_W2 = OFF_WHH + 192 * kHPitch;
constexpr int OFF_B1 = OFF_W2 + 16 * kHPitch;
constexpr int OFF_BIH = OFF_B1 + 64;
constexpr int OFF_BHH = OFF_BIH + 192;
constexpr int OFF_B2 = OFF_BHH + 192;
constexpr int LDS_FLOATS = OFF_B2 + 16;
}

__device__ __forceinline__ float bcastf(float v, int l) {
  return __int_as_float(__builtin_amdgcn_readlane(__float_as_int(v), l));
}

__global__ __launch_bounds__(512, 1)
void drqn_fused(const float* __restrict__ obs, const int* __restrict__ agent,
                const float* __restrict__ W1, const float* __restrict__ b1,
                const float* __restrict__ Wih, const float* __restrict__ Whh,
                const float* __restrict__ bih, const float* __restrict__ bhh,
                const float* __restrict__ W2, const float* __restrict__ b2,
                float* __restrict__ out) {
  using namespace fb;
  extern __shared__ float lds[];
  float* W1s = lds + OFF_W1; float* Wihs = lds + OFF_WIH;
  float* Whhs = lds + OFF_WHH; float* W2s = lds + OFF_W2;
  float* b1s = lds + OFF_B1; float* bihs = lds + OFF_BIH;
  float* bhhs = lds + OFF_BHH; float* b2s = lds + OFF_B2;
  const int tid = threadIdx.x;
  for (int i = tid; i < 64 * 136; i += 512) { int r = i / 136, c = i - r * 136; W1s[r * kW1Pitch + c] = W1[i]; }
  for (int i = tid; i < 192 * 64; i += 512) { int r = i >> 6, c = i & 63; Wihs[r * kHPitch + c] = Wih[i]; }
  for (int i = tid; i < 192 * 64; i += 512) { int r = i >> 6, c = i & 63; Whhs[r * kHPitch + c] = Whh[i]; }
  for (int i = tid; i < 16 * 64; i += 512) { int r = i >> 6, c = i & 63; W2s[r * kHPitch + c] = W2[i]; }
  if (tid < 64) b1s[tid] = b1[tid];
  if (tid < 192) bihs[tid] = bih[tid];
  if (tid < 192) bhhs[tid] = bhh[tid];
  if (tid < 16) b2s[tid] = b2[tid];
  __syncthreads();
  const int wave = tid >> 6, lane = tid & 63;
  const int s = blockIdx.x * 8 + wave;
  const int b = s >> 3, n = s & 7;
  const int acol = 128 + agent[n];
  const float* obase = obs + (((size_t)b * kT) * kN + n) * kObs;
  const size_t qbase = (((size_t)b * kT) * kN + n) * kOut;
  const size_t mbase = ((size_t)b * kT) * kN + n;
  float* outq = out;
  float* outmv = out + (size_t)kB * kT * kN * kOut;
  float* outma = outmv + (size_t)kB * kT * kN;
  float h = 0.f;
  float xa = obase[lane], xb = obase[64 + lane];
  #pragma unroll 1
  for (int t = 0; t < kT; ++t) {
    float xan = 0.f, xbn = 0.f;
    if (t + 1 < kT) { const float* p = obase + (size_t)(t + 1) * kN * kObs; xan = p[lane]; xbn = p[64 + lane]; }
    float acc = b1s[lane] + W1s[lane * kW1Pitch + acol];
    #pragma unroll
    for (int k = 0; k < 64; ++k) acc += W1s[lane * kW1Pitch + k] * bcastf(xa, k);
    #pragma unroll
    for (int k = 0; k < 64; ++k) acc += W1s[lane * kW1Pitch + 64 + k] * bcastf(xb, k);
    float a = fmaxf(acc, 0.f);
    float air = bihs[lane], aiz = bihs[64 + lane], ain = bihs[128 + lane];
    #pragma unroll
    for (int k = 0; k < 64; ++k) {
      float sa = bcastf(a, k);
      air += Wihs[lane * kHPitch + k] * sa;
      aiz += Wihs[(64 + lane) * kHPitch + k] * sa;
      ain += Wihs[(128 + lane) * kHPitch + k] * sa;
    }
    float ghr = bhhs[lane], ghz = bhhs[64 + lane], ghn = bhhs[128 + lane];
    #pragma unroll
    for (int k = 0; k < 64; ++k) {
      float sh = bcastf(h, k);
      ghr += Whhs[lane * kHPitch + k] * sh;
      ghz += Whhs[(64 + lane) * kHPitch + k] * sh;
      ghn += Whhs[(128 + lane) * kHPitch + k] * sh;
    }
    float rg = 1.f / (1.f + expf(-(air + ghr)));
    float zg = 1.f / (1.f + expf(-(aiz + ghz)));
    float ng = tanhf(ain + rg * ghn);
    h = (1.f - zg) * ng + zg * h;
    const int m = lane & 15;
    float q = b2s[m];
    #pragma unroll
    for (int k = 0; k < 64; ++k) q += W2s[m * kHPitch + k] * bcastf(h, k);
    if (lane < 16) outq[qbase + (size_t)t * kN * kOut + m] = q;
    float bv = q; int bi = m;
    #pragma unroll
    for (int d = 1; d < 16; d <<= 1) {
      float ov = __shfl_xor(bv, d, 16);
      int oi = __shfl_xor(bi, d, 16);
      if (ov > bv || (ov == bv && oi < bi)) { bv = ov; bi = oi; }
    }
    if (lane == 0) { outmv[mbase + (size_t)t * kN] = bv; outma[mbase + (size_t)t * kN] = (float)bi; }
    xa = xan; xb = xbn;
  }
}

extern "C" void kernel_launch(void* const* d_in, const int* in_sizes, int n_in,
                              void* d_out, int out_size, void* d_ws, size_t ws_size,
                              hipStream_t stream) {
  const float* obs  = (const float*)d_in[0];
  const int* agent  = (const int*)d_in[1];
  const float* W1   = (const float*)d_in[2];
  const float* b1   = (const float*)d_in[3];
  const float* Wih  = (const float*)d_in[4];
  const float* Whh  = (const float*)d_in[5];
  const float* bih  = (const float*)d_in[6];
  const float* bhh  = (const float*)d_in[7];
  const float* W2   = (const float*)d_in[8];
  const float* b2   = (const float*)d_in[9];
  float* out = (float*)d_out;

  if (ws_size >= kABytes + kGiBytes) {
    float* a_buf  = (float*)d_ws;
    float* gi_buf = (float*)((char*)d_ws + kABytes);
    fc1_k <<<dim3(2048), dim3(256), 0, stream>>>(obs, agent, W1, b1, a_buf);
    gi_k  <<<dim3(512), dim3(256), 0, stream>>>(a_buf, Wih, bih, gi_buf);
    gru7_k<<<dim3(2048), dim3(128), 0, stream>>>(gi_buf, Whh, bhh, W2, b2, out);
  } else {
    (void)hipFuncSetAttribute((const void*)drqn_fused,
                              hipFuncAttributeMaxDynamicSharedMemorySize,
                              fb::LDS_FLOATS * 4);
    drqn_fused<<<dim3(256), dim3(512), fb::LDS_FLOATS * 4, stream>>>(
        obs, agent, W1, b1, Wih, Whh, bih, bhh, W2, b2, out);
  }
}

// Round 16
// 582.167 us; speedup vs baseline: 2.3319x; 1.4501x over previous
//
#include <hip/hip_runtime.h>

// MultiAgentDRQN R16 = exact R10 configuration (best known: 596us).
// 15-round ledger: allocator caps recurrent kernels at 80-132 VGPR regardless
// of launch_bounds/WG-shape (R10/R11/R14/R15 nulls); weight sets > cap reload
// from cache every step; gate-split starves intensity (R13/R14); 2-seq/wave
// starves TLP (R12); split-K GRU pays barriers > reload savings (R15).
// Config: fc1_k (R8 split-K, VGPR~90) -> gi_k (R4, hoisted gi) -> gru3_k
// (1 wave/seq, no barriers, 128 VGPR, 74% VALUBusy). All fp32.
// Fallback: R1 fused kernel if ws too small.

namespace {
constexpr int kB = 256, kT = 200, kN = 8, kObs = 128, kH = 64, kOut = 16;
constexpr int kRows = kB * kT * kN;                  // 409600
constexpr size_t kABytes  = (size_t)kRows * 64 * 4;  // 100 MB
constexpr size_t kGiBytes = (size_t)kRows * 192 * 4; // 300 MB
}

// ------- fc1_k: a[r][64] = relu(x_r . W1^T + b1), split-K 2 waves/row --------
__global__ __launch_bounds__(256, 2)
void fc1_k(const float* __restrict__ obs, const int* __restrict__ agent,
           const float* __restrict__ W1, const float* __restrict__ b1,
           float* __restrict__ a_out) {
  __shared__ float xs[2][2][128];   // [engine][buf][k]
  __shared__ float ps[2][2][64];    // [engine][buf][out] partial sums
  __shared__ float ohs[512];        // ohs[n*64+l] = W1[l][128+agent[n]]
  const int tid = threadIdx.x, lane = tid & 63, w = tid >> 6;
  const int e = w >> 1, p = w & 1;  // engine, k-half

  for (int i = tid; i < 512; i += 256) {
    int n = i >> 6, l = i & 63;
    ohs[i] = W1[(size_t)l * 136 + 128 + agent[n]];
  }

  float4 wv[16];
  #pragma unroll
  for (int k = 0; k < 16; ++k)
    wv[k] = *(const float4*)(W1 + (size_t)lane * 136 + p * 64 + k * 4);
  const float b1r = b1[lane];       // used by finishing wave (p==1)

  constexpr int ROWS = 100;         // 4096 engines x 100 rows = 409600
  const int eng = blockIdx.x * 2 + e;
  const int r0 = eng * ROWS;
  const int et = p * 64 + lane;     // engine-local staging index [0,128)

  xs[e][0][et] = obs[(size_t)r0 * 128 + et];
  float xq = obs[(size_t)(r0 + 1) * 128 + et];
  __syncthreads();                  // covers ohs + row-0 staging

  #pragma unroll 1
  for (int i = 0; i < ROWS; ++i) {
    const int r = r0 + i;
    if (i + 1 < ROWS) xs[e][(i + 1) & 1][et] = xq;
    const int nr = (i + 2 < ROWS) ? (r0 + i + 2) : (r0 + ROWS - 1);
    xq = obs[(size_t)nr * 128 + et];

    const float* xb = xs[e][i & 1] + p * 64;
    float a0 = 0.f, a1 = 0.f, a2 = 0.f, a3 = 0.f;
    #pragma unroll
    for (int k = 0; k < 16; ++k) {
      float4 xp = *(const float4*)(xb + k * 4);   // same-addr broadcast read
      a0 = fmaf(wv[k].x, xp.x, a0);
      a1 = fmaf(wv[k].y, xp.y, a1);
      a2 = fmaf(wv[k].z, xp.z, a2);
      a3 = fmaf(wv[k].w, xp.w, a3);
    }
    const float part = (a0 + a1) + (a2 + a3);
    if (p == 0) ps[e][i & 1][lane] = part;
    __syncthreads();                // ps(i) visible; dbuf protects i+2 reuse
    if (p == 1) {
      float av = part + ps[e][i & 1][lane] + b1r + ohs[(r & 7) * 64 + lane];
      a_out[(size_t)r * 64 + lane] = fmaxf(av, 0.f);
    }
  }
}

// ---------------- gi_k: gi[r][192] = Wih . a_r + bih -------------------------
__global__ __launch_bounds__(256, 2)
void gi_k(const float* __restrict__ a_glob, const float* __restrict__ Wih,
          const float* __restrict__ bih, float* __restrict__ gi_out) {
  __shared__ float as_[4][2][64];
  const int tid = threadIdx.x, lane = tid & 63, w = tid >> 6;

  float wir[64], wiz[64], win_[64];
  #pragma unroll
  for (int k = 0; k < 64; k += 4) {
    *(float4*)&wir[k]  = *(const float4*)(Wih + (size_t)lane * 64 + k);
    *(float4*)&wiz[k]  = *(const float4*)(Wih + (size_t)(64 + lane) * 64 + k);
    *(float4*)&win_[k] = *(const float4*)(Wih + (size_t)(128 + lane) * 64 + k);
  }
  const float bir = bih[lane], biz = bih[64 + lane], bin_ = bih[128 + lane];

  const int gwave = blockIdx.x * 4 + w;   // 2048 waves x 200 rows
  const int r0 = gwave * 200;
  float (*ab)[64] = as_[w];

  ab[0][lane] = a_glob[(size_t)r0 * 64 + lane];
  float qA = a_glob[(size_t)(r0 + 1) * 64 + lane];
  float qB = a_glob[(size_t)(r0 + 2) * 64 + lane];

#define GI_BODY(T, Q, NEXT)                                                    \
  {                                                                            \
    const int t_ = (T);                                                        \
    if (t_ < 199) ab[(t_ + 1) & 1][lane] = Q;                                  \
    const int nr_ = (NEXT) > 199 ? 199 : (NEXT);                               \
    Q = a_glob[(size_t)(r0 + nr_) * 64 + lane];                                \
    const float* ap_ = ab[t_ & 1];                                             \
    float r0a = bir, r1a = 0.f, z0a = biz, z1a = 0.f, n0a = bin_, n1a = 0.f;   \
    _Pragma("unroll") for (int k = 0; k < 64; k += 4) {                        \
      float4 av = *(const float4*)(ap_ + k);                                   \
      r0a = fmaf(wir[k], av.x, r0a);  r1a = fmaf(wir[k + 1], av.y, r1a);       \
      r0a = fmaf(wir[k + 2], av.z, r0a); r1a = fmaf(wir[k + 3], av.w, r1a);    \
      z0a = fmaf(wiz[k], av.x, z0a);  z1a = fmaf(wiz[k + 1], av.y, z1a);       \
      z0a = fmaf(wiz[k + 2], av.z, z0a); z1a = fmaf(wiz[k + 3], av.w, z1a);    \
      n0a = fmaf(win_[k], av.x, n0a); n1a = fmaf(win_[k + 1], av.y, n1a);      \
      n0a = fmaf(win_[k + 2], av.z, n0a); n1a = fmaf(win_[k + 3], av.w, n1a);  \
    }                                                                          \
    float* gp_ = gi_out + (size_t)(r0 + t_) * 192;                             \
    gp_[lane] = r0a + r1a;                                                     \
    gp_[64 + lane] = z0a + z1a;                                                \
    gp_[128 + lane] = n0a + n1a;                                               \
  }

  #pragma unroll 1
  for (int i = 0; i < 200; i += 2) {
    GI_BODY(i + 0, qA, i + 3)
    GI_BODY(i + 1, qB, i + 4)
  }
#undef GI_BODY
}

// -------- gru3_k: 1 wave per sequence, no barriers. bounds(64,1) -------------
__global__ __launch_bounds__(64, 1)
void gru3_k(const float* __restrict__ gi_glob,
            const float* __restrict__ Whh, const float* __restrict__ bhh,
            const float* __restrict__ W2, const float* __restrict__ b2,
            float* __restrict__ out) {
  __shared__ float hs[64];
  const int lane = threadIdx.x;

  float whr[64], whz[64], whn[64];
  #pragma unroll
  for (int k = 0; k < 64; k += 4) {
    *(float4*)&whr[k] = *(const float4*)(Whh + (size_t)lane * 64 + k);
    *(float4*)&whz[k] = *(const float4*)(Whh + (size_t)(64 + lane) * 64 + k);
    *(float4*)&whn[k] = *(const float4*)(Whh + (size_t)(128 + lane) * 64 + k);
  }
  const float bhr = bhh[lane], bhz = bhh[64 + lane], bhn = bhh[128 + lane];
  const int m = lane & 15, qt = lane >> 4;
  float w2r[16];
  #pragma unroll
  for (int j = 0; j < 16; j += 4)
    *(float4*)&w2r[j] = *(const float4*)(W2 + (size_t)m * 64 + qt * 16 + j);
  const float b2r = b2[m];

  const int s = blockIdx.x;              // sequence = b*8 + n
  const int b = s >> 3, n = s & 7;
  const size_t rbase = (size_t)b * 1600 + n;   // r(t) = rbase + 8t

  float* outq  = out;
  float* outmv = out + (size_t)kRows * 16;
  float* outma = outmv + kRows;

  hs[lane] = 0.f;
  float h = 0.f;

  // prefetch gi for t=0 (slot A) and t=1 (slot B)
  const float* gp0 = gi_glob + rbase * 192;
  float gA0 = gp0[lane], gA1 = gp0[64 + lane], gA2 = gp0[128 + lane];
  const float* gp1 = gi_glob + (rbase + 8) * 192;
  float gB0 = gp1[lane], gB1 = gp1[64 + lane], gB2 = gp1[128 + lane];

#define GRU_STEP(T, G0, G1, G2, TN)                                            \
  {                                                                            \
    const int t_ = (T);                                                        \
    const size_t r_ = rbase + (size_t)t_ * 8;                                  \
    float hr0 = bhr, hr1 = 0.f, hz0 = bhz, hz1 = 0.f, hn0 = bhn, hn1 = 0.f;    \
    _Pragma("unroll") for (int k = 0; k < 64; k += 4) {                        \
      float4 hp = *(const float4*)(hs + k);                                    \
      hr0 = fmaf(whr[k], hp.x, hr0);  hr1 = fmaf(whr[k + 1], hp.y, hr1);       \
      hr0 = fmaf(whr[k + 2], hp.z, hr0); hr1 = fmaf(whr[k + 3], hp.w, hr1);    \
      hz0 = fmaf(whz[k], hp.x, hz0);  hz1 = fmaf(whz[k + 1], hp.y, hz1);       \
      hz0 = fmaf(whz[k + 2], hp.z, hz0); hz1 = fmaf(whz[k + 3], hp.w, hz1);    \
      hn0 = fmaf(whn[k], hp.x, hn0);  hn1 = fmaf(whn[k + 1], hp.y, hn1);       \
      hn0 = fmaf(whn[k + 2], hp.z, hn0); hn1 = fmaf(whn[k + 3], hp.w, hn1);    \
    }                                                                          \
    const float rg = 1.f / (1.f + __expf(-((G0) + hr0 + hr1)));                \
    const float zg = 1.f / (1.f + __expf(-((G1) + hz0 + hz1)));                \
    const float e2 = __expf(2.f * ((G2) + rg * (hn0 + hn1)));                  \
    const float ng = 1.f - 2.f / (e2 + 1.f);                                   \
    h = (1.f - zg) * ng + zg * h;                                              \
    hs[lane] = h;                                                              \
    const int tn_ = (TN) > 199 ? 199 : (TN);                                   \
    const float* gp_ = gi_glob + (rbase + (size_t)tn_ * 8) * 192;              \
    G0 = gp_[lane]; G1 = gp_[64 + lane]; G2 = gp_[128 + lane];                 \
    float q0 = 0.f, q1 = 0.f;                                                  \
    _Pragma("unroll") for (int j = 0; j < 16; j += 4) {                        \
      float4 hp = *(const float4*)(hs + qt * 16 + j);                          \
      q0 = fmaf(w2r[j], hp.x, q0);     q1 = fmaf(w2r[j + 1], hp.y, q1);        \
      q0 = fmaf(w2r[j + 2], hp.z, q0); q1 = fmaf(w2r[j + 3], hp.w, q1);        \
    }                                                                          \
    float q = q0 + q1;                                                         \
    q += __shfl_xor(q, 16);                                                    \
    q += __shfl_xor(q, 32);                                                    \
    q += b2r;                                                                  \
    if (lane < 16) outq[r_ * 16 + m] = q;                                      \
    float bv = q; int bi = m;                                                  \
    _Pragma("unroll") for (int d = 1; d < 16; d <<= 1) {                       \
      float ov = __shfl_xor(bv, d, 16);                                        \
      int oi = __shfl_xor(bi, d, 16);                                          \
      if (ov > bv || (ov == bv && oi < bi)) { bv = ov; bi = oi; }              \
    }                                                                          \
    if (lane == 0) { outmv[r_] = bv; outma[r_] = (float)bi; }                  \
  }

  #pragma unroll 1
  for (int t = 0; t < 200; t += 2) {
    GRU_STEP(t, gA0, gA1, gA2, t + 2)
    GRU_STEP(t + 1, gB0, gB1, gB2, t + 3)
  }
#undef GRU_STEP
}

// ---------------- R1 fallback (no/small workspace) ---------------------------
namespace fb {
constexpr int kW1Pitch = 137, kHPitch = 65;
constexpr int OFF_W1 = 0;
constexpr int OFF_WIH = OFF_W1 + 64 * kW1Pitch;
constexpr int OFF_WHH = OFF_WIH + 192 * kHPitch;
constexpr int OFF_W2 = OFF_WHH + 192 * kHPitch;
constexpr int OFF_B1 = OFF_W2 + 16 * kHPitch;
constexpr int OFF_BIH = OFF_B1 + 64;
constexpr int OFF_BHH = OFF_BIH + 192;
constexpr int OFF_B2 = OFF_BHH + 192;
constexpr int LDS_FLOATS = OFF_B2 + 16;
}

__device__ __forceinline__ float bcastf(float v, int l) {
  return __int_as_float(__builtin_amdgcn_readlane(__float_as_int(v), l));
}

__global__ __launch_bounds__(512, 1)
void drqn_fused(const float* __restrict__ obs, const int* __restrict__ agent,
                const float* __restrict__ W1, const float* __restrict__ b1,
                const float* __restrict__ Wih, const float* __restrict__ Whh,
                const float* __restrict__ bih, const float* __restrict__ bhh,
                const float* __restrict__ W2, const float* __restrict__ b2,
                float* __restrict__ out) {
  using namespace fb;
  extern __shared__ float lds[];
  float* W1s = lds + OFF_W1; float* Wihs = lds + OFF_WIH;
  float* Whhs = lds + OFF_WHH; float* W2s = lds + OFF_W2;
  float* b1s = lds + OFF_B1; float* bihs = lds + OFF_BIH;
  float* bhhs = lds + OFF_BHH; float* b2s = lds + OFF_B2;
  const int tid = threadIdx.x;
  for (int i = tid; i < 64 * 136; i += 512) { int r = i / 136, c = i - r * 136; W1s[r * kW1Pitch + c] = W1[i]; }
  for (int i = tid; i < 192 * 64; i += 512) { int r = i >> 6, c = i & 63; Wihs[r * kHPitch + c] = Wih[i]; }
  for (int i = tid; i < 192 * 64; i += 512) { int r = i >> 6, c = i & 63; Whhs[r * kHPitch + c] = Whh[i]; }
  for (int i = tid; i < 16 * 64; i += 512) { int r = i >> 6, c = i & 63; W2s[r * kHPitch + c] = W2[i]; }
  if (tid < 64) b1s[tid] = b1[tid];
  if (tid < 192) bihs[tid] = bih[tid];
  if (tid < 192) bhhs[tid] = bhh[tid];
  if (tid < 16) b2s[tid] = b2[tid];
  __syncthreads();
  const int wave = tid >> 6, lane = tid & 63;
  const int s = blockIdx.x * 8 + wave;
  const int b = s >> 3, n = s & 7;
  const int acol = 128 + agent[n];
  const float* obase = obs + (((size_t)b * kT) * kN + n) * kObs;
  const size_t qbase = (((size_t)b * kT) * kN + n) * kOut;
  const size_t mbase = ((size_t)b * kT) * kN + n;
  float* outq = out;
  float* outmv = out + (size_t)kB * kT * kN * kOut;
  float* outma = outmv + (size_t)kB * kT * kN;
  float h = 0.f;
  float xa = obase[lane], xb = obase[64 + lane];
  #pragma unroll 1
  for (int t = 0; t < kT; ++t) {
    float xan = 0.f, xbn = 0.f;
    if (t + 1 < kT) { const float* p = obase + (size_t)(t + 1) * kN * kObs; xan = p[lane]; xbn = p[64 + lane]; }
    float acc = b1s[lane] + W1s[lane * kW1Pitch + acol];
    #pragma unroll
    for (int k = 0; k < 64; ++k) acc += W1s[lane * kW1Pitch + k] * bcastf(xa, k);
    #pragma unroll
    for (int k = 0; k < 64; ++k) acc += W1s[lane * kW1Pitch + 64 + k] * bcastf(xb, k);
    float a = fmaxf(acc, 0.f);
    float air = bihs[lane], aiz = bihs[64 + lane], ain = bihs[128 + lane];
    #pragma unroll
    for (int k = 0; k < 64; ++k) {
      float sa = bcastf(a, k);
      air += Wihs[lane * kHPitch + k] * sa;
      aiz += Wihs[(64 + lane) * kHPitch + k] * sa;
      ain += Wihs[(128 + lane) * kHPitch + k] * sa;
    }
    float ghr = bhhs[lane], ghz = bhhs[64 + lane], ghn = bhhs[128 + lane];
    #pragma unroll
    for (int k = 0; k < 64; ++k) {
      float sh = bcastf(h, k);
      ghr += Whhs[lane * kHPitch + k] * sh;
      ghz += Whhs[(64 + lane) * kHPitch + k] * sh;
      ghn += Whhs[(128 + lane) * kHPitch + k] * sh;
    }
    float rg = 1.f / (1.f + expf(-(air + ghr)));
    float zg = 1.f / (1.f + expf(-(aiz + ghz)));
    float ng = tanhf(ain + rg * ghn);
    h = (1.f - zg) * ng + zg * h;
    const int m = lane & 15;
    float q = b2s[m];
    #pragma unroll
    for (int k = 0; k < 64; ++k) q += W2s[m * kHPitch + k] * bcastf(h, k);
    if (lane < 16) outq[qbase + (size_t)t * kN * kOut + m] = q;
    float bv = q; int bi = m;
    #pragma unroll
    for (int d = 1; d < 16; d <<= 1) {
      float ov = __shfl_xor(bv, d, 16);
      int oi = __shfl_xor(bi, d, 16);
      if (ov > bv || (ov == bv && oi < bi)) { bv = ov; bi = oi; }
    }
    if (lane == 0) { outmv[mbase + (size_t)t * kN] = bv; outma[mbase + (size_t)t * kN] = (float)bi; }
    xa = xan; xb = xbn;
  }
}

extern "C" void kernel_launch(void* const* d_in, const int* in_sizes, int n_in,
                              void* d_out, int out_size, void* d_ws, size_t ws_size,
                              hipStream_t stream) {
  const float* obs  = (const float*)d_in[0];
  const int* agent  = (const int*)d_in[1];
  const float* W1   = (const float*)d_in[2];
  const float* b1   = (const float*)d_in[3];
  const float* Wih  = (const float*)d_in[4];
  const float* Whh  = (const float*)d_in[5];
  const float* bih  = (const float*)d_in[6];
  const float* bhh  = (const float*)d_in[7];
  const float* W2   = (const float*)d_in[8];
  const float* b2   = (const float*)d_in[9];
  float* out = (float*)d_out;

  if (ws_size >= kABytes + kGiBytes) {
    float* a_buf  = (float*)d_ws;
    float* gi_buf = (float*)((char*)d_ws + kABytes);
    fc1_k <<<dim3(2048), dim3(256), 0, stream>>>(obs, agent, W1, b1, a_buf);
    gi_k  <<<dim3(512), dim3(256), 0, stream>>>(a_buf, Wih, bih, gi_buf);
    gru3_k<<<dim3(2048), dim3(64), 0, stream>>>(gi_buf, Whh, bhh, W2, b2, out);
  } else {
    (void)hipFuncSetAttribute((const void*)drqn_fused,
                              hipFuncAttributeMaxDynamicSharedMemorySize,
                              fb::LDS_FLOATS * 4);
    drqn_fused<<<dim3(256), dim3(512), fb::LDS_FLOATS * 4, stream>>>(
        obs, agent, W1, b1, Wih, Whh, bih, bhh, W2, b2, out);
  }
}